// Round 14
// baseline (198.911 us; speedup 1.0000x reference)
//
#include <hip/hip_runtime.h>
#include <hip/hip_bf16.h>
#include <math.h>

#define N 8192
#define D 256
#define MARGIN 1.0f

#define BM 128
#define BN 128
#define NCH 4            // K-chunks of 64 fp16 elems (128B per row)
#define NB (N / BM)      // 64
#define NTRI (NB * (NB + 1) / 2)   // 2080
#define NCONV (N * D / 4 / 256)    // 2048 conversion blocks
#define NCLS 512
#define CCAP 128         // class member capacity (mean 16, P(>128) ~ 0)

typedef __attribute__((ext_vector_type(8))) _Float16 half8;
typedef __attribute__((ext_vector_type(4))) _Float16 half4;
typedef __attribute__((ext_vector_type(4))) float f32x4;
typedef unsigned int uint32;
typedef unsigned long long u64;

// ---------------------------------------------------------------------------
// k_prep: one launch does everything before the GEMM.
//   blocks [0, NCONV):       f32 -> fp16 conversion (block 0 also zeroes
//                            the acc_pack/counter finish cells)
//   blocks [NCONV, +NCLS):   per-class exact-f32 d_pos. Scan labels once
//                            (coalesced, L2-hot), collect members in LDS,
//                            one wave per member computes max same-label
//                            dist. fmax is associative -> deterministic.
// ---------------------------------------------------------------------------
__global__ __launch_bounds__(256) void k_prep(const float* __restrict__ x,
                                              const int* __restrict__ labels,
                                              _Float16* __restrict__ hp,
                                              float* __restrict__ dpos,
                                              u64* __restrict__ acc_pack,
                                              unsigned* __restrict__ counter) {
    __shared__ int mem[CCAP];
    __shared__ int nmem;
    const int b = blockIdx.x;

    if (b < NCONV) {
        int i = b * 256 + threadIdx.x;
        float4 v = reinterpret_cast<const float4*>(x)[i];
        half4 h;
        h[0] = (_Float16)v.x; h[1] = (_Float16)v.y;
        h[2] = (_Float16)v.z; h[3] = (_Float16)v.w;
        reinterpret_cast<half4*>(hp)[i] = h;
        if (b == 0 && threadIdx.x == 0) {
            *acc_pack = 0ull;
            *counter = 0u;
        }
        return;
    }

    const int c = b - NCONV;
    if (threadIdx.x == 0) nmem = 0;
    __syncthreads();
    for (int base = 0; base < N; base += 256) {
        int j = base + threadIdx.x;
        if (labels[j] == c) {
            int p = atomicAdd(&nmem, 1);
            if (p < CCAP) mem[p] = j;
        }
    }
    __syncthreads();
    int M = nmem < CCAP ? nmem : CCAP;
    const int wv = threadIdx.x >> 6, lane = threadIdx.x & 63;

    for (int e = wv; e < M; e += 4) {
        const int i = mem[e];
        float4 xi = reinterpret_cast<const float4*>(x + (size_t)i * D)[lane];
        float sqi = xi.x * xi.x + xi.y * xi.y + xi.z * xi.z + xi.w * xi.w;
        for (int m = 32; m >= 1; m >>= 1) sqi += __shfl_xor(sqi, m, 64);
        float dp = -1.0f;
        for (int f = 0; f < M; ++f) {
            const int j = mem[f];
            if (j == i) continue;
            float4 xj = reinterpret_cast<const float4*>(x + (size_t)j * D)[lane];
            float dotp = xi.x * xj.x + xi.y * xj.y + xi.z * xj.z + xi.w * xj.w;
            float sqj = xj.x * xj.x + xj.y * xj.y + xj.z * xj.z + xj.w * xj.w;
            for (int m = 32; m >= 1; m >>= 1) {
                dotp += __shfl_xor(dotp, m, 64);
                sqj += __shfl_xor(sqj, m, 64);
            }
            float sqd = fmaxf(sqi + sqj - 2.0f * dotp, 0.0f);
            float dist = sqd > 0.0f ? sqrtf(sqd) : 0.0f;
            dp = fmaxf(dp, dist);
        }
        if (lane == 0) dpos[i] = dp;
    }
}

// ---------------------------------------------------------------------------
// k_main: symmetric fp16 MFMA GEMM, 8 waves (2x4), 64x32/wave, acc + accT.
// r14: KEY-FREE epilogue -- min-dist == max-acc (fsq = 2-2a monotone
// decreasing), so track plain float maxima: an = max a over diff-label,
// ag = max a over {diff-label, a < aHi} (semi window upper bound checked
// later). fmax associative -> plain partial stores stay deterministic.
// No quantization anywhere. Core staging/swizzle unchanged (0 conflicts).
// ---------------------------------------------------------------------------
__global__ __launch_bounds__(512) void k_main(const _Float16* __restrict__ hp,
                                              const int* __restrict__ labels,
                                              const float* __restrict__ dpos,
                                              float* __restrict__ pr_n,
                                              float* __restrict__ pr_s,
                                              float* __restrict__ pc_n,
                                              float* __restrict__ pc_s) {
    __shared__ char Abuf[2][BM * 128];   // 16 KB each
    __shared__ char Bbuf[2][BN * 128];
    __shared__ float rHi[BM], cHi[BN];
    __shared__ int rlab[BM], clab[BN];
    __shared__ float tmpn[4][BM], tmps[4][BM];

    const int t = threadIdx.x;
    int tb = blockIdx.x;
    // triangular decode: tb -> (by, bx), by <= bx
    int by = (int)((2 * NB + 1 - sqrtf((float)((2 * NB + 1) * (2 * NB + 1)) -
                                       8.0f * (float)tb)) * 0.5f);
    if (by < 0) by = 0;
    if (by > NB - 1) by = NB - 1;
    while (by > 0 && (by * NB - by * (by - 1) / 2) > tb) --by;
    while (((by + 1) * NB - (by + 1) * by / 2) <= tb) ++by;
    const int bx = by + (tb - (by * NB - by * (by - 1) / 2));
    const int r0 = by * BM, c0 = bx * BN;

    const int w = t >> 6, lane = t & 63;
    const int wr = w >> 2, wc = w & 3;   // 2x4 wave grid; 64x32 per wave

    if (t < BM) {
        rlab[t] = labels[r0 + t];
        float dp = dpos[r0 + t];
        rHi[t] = (2.0f - dp * dp) * 0.5f;   // a < aHi <=> dist > dp
    } else if (t < 256) {
        int u = t - BM;
        clab[u] = labels[c0 + u];
        float dp = dpos[c0 + u];
        cHi[u] = (2.0f - dp * dp) * 0.5f;
    }

    f32x4 acc[4][2] = {};    // [m][n]
    f32x4 accT[2][4] = {};   // [n][m]

    // hoisted staging addresses: wave w stages chunks {w, w+8} per buffer.
    const int srow = lane >> 3;
    const int scol = ((lane & 7) ^ srow) << 3;   // fp16-elem offset
    const _Float16* gA0 = hp + (size_t)(r0 + srow) * D + scol + (size_t)w * 8 * D;
    const _Float16* gB0 = hp + (size_t)(c0 + srow) * D + scol + (size_t)w * 8 * D;
    const int ldso = w * 1024 + lane * 16;

#define STAGE(bufA, bufB, k0e)                                                  \
    {                                                                           \
        _Pragma("unroll")                                                       \
        for (int q = 0; q < 2; ++q) {                                           \
            const _Float16* gpa = gA0 + q * (8 * 8 * D) + (k0e);                \
            const _Float16* gpb = gB0 + q * (8 * 8 * D) + (k0e);                \
            char* lpa = (bufA) + q * 8192 + ldso;                               \
            char* lpb = (bufB) + q * 8192 + ldso;                               \
            __builtin_amdgcn_global_load_lds(                                   \
                (__attribute__((address_space(1))) void*)(void*)gpa,            \
                (__attribute__((address_space(3))) void*)lpa, 16, 0, 0);        \
            __builtin_amdgcn_global_load_lds(                                   \
                (__attribute__((address_space(1))) void*)(void*)gpb,            \
                (__attribute__((address_space(3))) void*)lpb, 16, 0, 0);        \
        }                                                                       \
    }

    STAGE(Abuf[0], Bbuf[0], 0);
    asm volatile("s_waitcnt vmcnt(0)" ::: "memory");
    __syncthreads();

    const int g2 = lane >> 4;
    const int lr = lane & 15;
    const int rsw = lr & 7;

#pragma unroll 1
    for (int s = 0; s < NCH; ++s) {
        const int cur = s & 1;
        if (s < NCH - 1) STAGE(Abuf[cur ^ 1], Bbuf[cur ^ 1], (s + 1) * 64);

#pragma unroll
        for (int kk = 0; kk < 2; ++kk) {
            const int cb = kk * 64 + (g2 << 4);
            half8 aF[4], bF[2];
#pragma unroll
            for (int m = 0; m < 4; ++m) {
                int ra = wr * 64 + m * 16 + lr;
                aF[m] = *reinterpret_cast<const half8*>(
                    Abuf[cur] + ra * 128 + (cb ^ (rsw << 4)));
            }
#pragma unroll
            for (int n = 0; n < 2; ++n) {
                int rb = wc * 32 + n * 16 + lr;
                bF[n] = *reinterpret_cast<const half8*>(
                    Bbuf[cur] + rb * 128 + (cb ^ (rsw << 4)));
            }
#pragma unroll
            for (int m = 0; m < 4; ++m)
#pragma unroll
                for (int n = 0; n < 2; ++n)
                    acc[m][n] = __builtin_amdgcn_mfma_f32_16x16x32_f16(
                        aF[m], bF[n], acc[m][n], 0, 0, 0);
#pragma unroll
            for (int n = 0; n < 2; ++n)
#pragma unroll
                for (int m = 0; m < 4; ++m)
                    accT[n][m] = __builtin_amdgcn_mfma_f32_16x16x32_f16(
                        bF[n], aF[m], accT[n][m], 0, 0, 0);
        }
        __syncthreads();
    }
#undef STAGE

    // ---- epilogue: key-free float maxima ----
    const float NINF = -__builtin_inff();

    int rowm[4]; int rlm[4]; float rHim[4];
#pragma unroll
    for (int m = 0; m < 4; ++m) {
        rowm[m] = wr * 64 + m * 16 + lr;
        rlm[m] = rlab[rowm[m]];
        rHim[m] = rHi[rowm[m]];
    }
    int4 clA = *reinterpret_cast<const int4*>(&clab[wc * 32 + g2 * 4]);
    int4 clB = *reinterpret_cast<const int4*>(&clab[wc * 32 + 16 + g2 * 4]);
    const int clv[8] = {clA.x, clA.y, clA.z, clA.w, clB.x, clB.y, clB.z, clB.w};
    int coln[2]; int cln[2]; float cHin[2];
#pragma unroll
    for (int n = 0; n < 2; ++n) {
        coln[n] = wc * 32 + n * 16 + lr;
        cln[n] = clab[coln[n]];
        cHin[n] = cHi[coln[n]];
    }
    int rlq[16];
#pragma unroll
    for (int m = 0; m < 4; ++m) {
        int4 rv = *reinterpret_cast<const int4*>(&rlab[wr * 64 + m * 16 + g2 * 4]);
        rlq[m * 4 + 0] = rv.x; rlq[m * 4 + 1] = rv.y;
        rlq[m * 4 + 2] = rv.z; rlq[m * 4 + 3] = rv.w;
    }

    // row pass via accT: anchor row on lane dim, cols in-lane
#pragma unroll
    for (int m = 0; m < 4; ++m) {
        const int rl = rlm[m];
        const float aHi = rHim[m];
        float an = NINF, ag = NINF;
#pragma unroll
        for (int n = 0; n < 2; ++n)
#pragma unroll
            for (int reg = 0; reg < 4; ++reg) {
                float a = accT[n][m][reg];
                bool neq = (rl != clv[n * 4 + reg]);
                an = fmaxf(an, neq ? a : NINF);
                ag = fmaxf(ag, (neq && a < aHi) ? a : NINF);
            }
        an = fmaxf(an, __shfl_xor(an, 16, 64));
        an = fmaxf(an, __shfl_xor(an, 32, 64));
        ag = fmaxf(ag, __shfl_xor(ag, 16, 64));
        ag = fmaxf(ag, __shfl_xor(ag, 32, 64));
        if (g2 == 0) {
            tmpn[wc][rowm[m]] = an;
            tmps[wc][rowm[m]] = ag;
        }
    }
    __syncthreads();
    if (t < BM) {
        float a0 = fmaxf(tmpn[0][t], tmpn[1][t]);
        float a1 = fmaxf(tmpn[2][t], tmpn[3][t]);
        pr_n[(size_t)tb * BM + t] = fmaxf(a0, a1);
        float b0 = fmaxf(tmps[0][t], tmps[1][t]);
        float b1 = fmaxf(tmps[2][t], tmps[3][t]);
        pr_s[(size_t)tb * BM + t] = fmaxf(b0, b1);
    }
    __syncthreads();

    // col pass via acc: anchor col on lane dim, rows in-lane
#pragma unroll
    for (int n = 0; n < 2; ++n) {
        const int cl = cln[n];
        const float aHi = cHin[n];
        float an = NINF, ag = NINF;
#pragma unroll
        for (int m = 0; m < 4; ++m)
#pragma unroll
            for (int reg = 0; reg < 4; ++reg) {
                float a = acc[m][n][reg];
                bool neq = (cl != rlq[m * 4 + reg]);
                an = fmaxf(an, neq ? a : NINF);
                ag = fmaxf(ag, (neq && a < aHi) ? a : NINF);
            }
        an = fmaxf(an, __shfl_xor(an, 16, 64));
        an = fmaxf(an, __shfl_xor(an, 32, 64));
        ag = fmaxf(ag, __shfl_xor(ag, 16, 64));
        ag = fmaxf(ag, __shfl_xor(ag, 32, 64));
        if (lane < 16) {
            tmpn[wr][coln[n]] = an;
            tmps[wr][coln[n]] = ag;
        }
    }
    __syncthreads();
    if (t < BN) {
        pc_n[(size_t)tb * BN + t] = fmaxf(tmpn[0][t], tmpn[1][t]);
        pc_s[(size_t)tb * BN + t] = fmaxf(tmps[0][t], tmps[1][t]);
    }
}

// ---------------------------------------------------------------------------
// k_finish: 64 blocks, one per anchor block-row. Coalesced fmax folds of
// the per-tile partials, then per-anchor loss straight from the exact f32
// maxima: has_semi <=> ag > aLo; d_neg = sqrt(2 - 2*a_sel). Deterministic
// packed-integer atomicAdd; last block writes the mean.
// ---------------------------------------------------------------------------
__global__ __launch_bounds__(256) void k_finish(const float* __restrict__ dpos,
                                                const float* __restrict__ pr_n,
                                                const float* __restrict__ pr_s,
                                                const float* __restrict__ pc_n,
                                                const float* __restrict__ pc_s,
                                                u64* __restrict__ acc_pack,
                                                unsigned* __restrict__ counter,
                                                float* __restrict__ out) {
    __shared__ float shn[2][128], shs[2][128];
    __shared__ u64 wpart[2];
    const int q = blockIdx.x;
    const int t = threadIdx.x;
    const int half = t >> 7, a = t & 127;
    const int Lr = NB - q;
    const int base = q * NB - q * (q - 1) / 2;
    const int ntiles = Lr + q + 1;
    const float NINF = -__builtin_inff();

    float an = NINF, ag = NINF;
    for (int u = half; u < ntiles; u += 2) {
        size_t off;
        const float *Pn, *Ps;
        if (u < Lr) {
            off = (size_t)(base + u) * BM + a;
            Pn = pr_n; Ps = pr_s;
        } else {
            int byy = u - Lr;    // 0..q
            int tb2 = byy * NB - byy * (byy - 1) / 2 + (q - byy);
            off = (size_t)tb2 * BN + a;
            Pn = pc_n; Ps = pc_s;
        }
        an = fmaxf(an, Pn[off]);
        ag = fmaxf(ag, Ps[off]);
    }
    shn[half][a] = an;
    shs[half][a] = ag;
    __syncthreads();

    u64 pack = 0;
    if (t < 128) {
        an = fmaxf(shn[0][t], shn[1][t]);
        ag = fmaxf(shs[0][t], shs[1][t]);
        float dp = dpos[q * 128 + t];
        if (dp >= 0.0f && an > -1e37f) {
            float dphi = dp + MARGIN;
            float aLo = (2.0f - dphi * dphi) * 0.5f;   // a > aLo <=> dist < dp+m
            float asel = (ag > aLo) ? ag : an;
            float fsq = fmaxf(fmaf(-2.0f, asel, 2.0f), 0.0f);
            float dn = sqrtf(fsq);
            float l = fmaxf(dp - dn + MARGIN, 0.0f);
            u64 lq = (u64)(l * 1073741824.0f + 0.5f);   // 2^30 fixed point
            pack = (lq << 16) | 1ull;
        }
    }
    for (int m = 1; m <= 32; m <<= 1) pack += __shfl_xor(pack, m, 64);
    if (t < 128 && (t & 63) == 0) wpart[t >> 6] = pack;
    __syncthreads();
    if (t == 0) {
        atomicAdd(acc_pack, wpart[0] + wpart[1]);
        __threadfence();
        unsigned old = atomicAdd(counter, 1u);
        if (old == gridDim.x - 1) {
            u64 val = atomicAdd(acc_pack, (u64)0);
            double s = (double)(val >> 16) * (1.0 / 1073741824.0);
            double c = (double)(val & 0xFFFFull);
            out[0] = (float)(s / c);
        }
    }
}

// ---------------------------------------------------------------------------
extern "C" void kernel_launch(void* const* d_in, const int* in_sizes, int n_in,
                              void* d_out, int out_size, void* d_ws, size_t ws_size,
                              hipStream_t stream) {
    const float* x = (const float*)d_in[0];
    const int* labels = (const int*)d_in[1];
    float* out = (float*)d_out;

    // ws layout:
    // acc_pack u64 | counter u32 | pad u32 | dpos[N] f32
    // | hp[N*D] fp16 (4MB) | pr_n | pr_s | pc_n | pc_s (f32, 1.06MB each)
    u64* acc_pack = (u64*)d_ws;
    unsigned* counter = (unsigned*)(acc_pack + 1);
    float* dpos = (float*)(counter + 2);
    _Float16* hp = (_Float16*)(dpos + N);
    float* pr_n = (float*)(hp + (size_t)N * D);
    float* pr_s = pr_n + (size_t)NTRI * BM;
    float* pc_n = pr_s + (size_t)NTRI * BM;
    float* pc_s = pc_n + (size_t)NTRI * BM;

    hipLaunchKernelGGL(k_prep, dim3(NCONV + NCLS), dim3(256), 0, stream,
                       x, labels, hp, dpos, acc_pack, counter);
    hipLaunchKernelGGL(k_main, dim3(NTRI), dim3(512), 0, stream,
                       hp, labels, dpos, pr_n, pr_s, pc_n, pc_s);
    hipLaunchKernelGGL(k_finish, dim3(NB), dim3(256), 0, stream,
                       dpos, pr_n, pr_s, pc_n, pc_s, acc_pack, counter, out);
}

// Round 15
// 98.413 us; speedup vs baseline: 2.0212x; 2.0212x over previous
//
#include <hip/hip_runtime.h>
#include <hip/hip_bf16.h>
#include <math.h>

#define N 8192
#define D 256
#define MARGIN 1.0f

#define BM 128
#define BN 128
#define NCH 4            // K-chunks of 64 fp16 elems (128B per row)
#define NB (N / BM)      // 64
#define NTRI (NB * (NB + 1) / 2)   // 2080
#define NCONV (N * D / 4 / 256)    // 2048 conversion blocks
#define NCLS 512
#define CCAP 64          // class member capacity (mean 16, max ~35 here)
#define RPITCH 257       // padded row pitch (floats) -> conflict-free LDS

typedef __attribute__((ext_vector_type(8))) _Float16 half8;
typedef __attribute__((ext_vector_type(4))) _Float16 half4;
typedef __attribute__((ext_vector_type(4))) float f32x4;
typedef unsigned int uint32;
typedef unsigned long long u64;

// ---------------------------------------------------------------------------
// k_prep: blocks [0,NCONV): f32->fp16 conversion (+ block 0 zeroes finish
// cells). Blocks [NCONV,+NCLS): per-class exact-f32 d_pos, LDS-resident:
// scan labels -> load M member rows into padded LDS once (coalesced) ->
// per-member sq -> ONE THREAD PER (i,j) PAIR does the 256-dim dot from LDS
// and one LDS atomicMax on sqd bits. No global-latency serial chains.
// ---------------------------------------------------------------------------
__global__ __launch_bounds__(256) void k_prep(const float* __restrict__ x,
                                              const int* __restrict__ labels,
                                              _Float16* __restrict__ hp,
                                              float* __restrict__ dpos,
                                              u64* __restrict__ acc_pack,
                                              unsigned* __restrict__ counter) {
    const int b = blockIdx.x;
    const int t = threadIdx.x;

    if (b < NCONV) {
        int i = b * 256 + t;
        float4 v = reinterpret_cast<const float4*>(x)[i];
        half4 h;
        h[0] = (_Float16)v.x; h[1] = (_Float16)v.y;
        h[2] = (_Float16)v.z; h[3] = (_Float16)v.w;
        reinterpret_cast<half4*>(hp)[i] = h;
        if (b == 0 && t == 0) {
            *acc_pack = 0ull;
            *counter = 0u;
        }
        return;
    }

    __shared__ float rows[CCAP * RPITCH];   // 65792 B
    __shared__ float sqv[CCAP];
    __shared__ int dpv[CCAP];               // sqd bits (>=0 -> int cmp ok)
    __shared__ int mem[CCAP];
    __shared__ int nmem;

    const int c = b - NCONV;
    if (t == 0) nmem = 0;
    if (t < CCAP) dpv[t] = 0;
    __syncthreads();
    for (int base = 0; base < N; base += 256) {
        int j = base + t;
        if (labels[j] == c) {
            int p = atomicAdd(&nmem, 1);
            if (p < CCAP) mem[p] = j;
        }
    }
    __syncthreads();
    const int M = nmem < CCAP ? nmem : CCAP;

    // load member rows (coalesced, once)
    for (int r = 0; r < M; ++r)
        rows[r * RPITCH + t] = x[(size_t)mem[r] * D + t];
    __syncthreads();

    // per-member squared norm (thread p handles member p)
    if (t < M) {
        const float* rp = &rows[t * RPITCH];
        float s = 0.0f;
        for (int d = 0; d < D; ++d) s += rp[d] * rp[d];
        sqv[t] = s;
    }
    __syncthreads();

    // one thread per ordered pair (i,j); update dpv[i]
    for (int p = t; p < M * M; p += 256) {
        int i = p / M, j = p - i * M;
        const float* ri = &rows[i * RPITCH];
        const float* rj = &rows[j * RPITCH];
        float dot = 0.0f;
        for (int d = 0; d < D; ++d) dot = fmaf(ri[d], rj[d], dot);
        float sqd = fmaxf(sqv[i] + sqv[j] - 2.0f * dot, 0.0f);
        if (j != i) atomicMax(&dpv[i], __float_as_int(sqd));
    }
    __syncthreads();
    if (t < M)
        dpos[mem[t]] = (M > 1) ? sqrtf(__int_as_float(dpv[t])) : -1.0f;
}

// ---------------------------------------------------------------------------
// k_main: symmetric fp16 MFMA GEMM, 8 waves (2x4), 64x32/wave, acc + accT.
// Key-free epilogue (r14-proven): min-dist == max-acc; track an = max a over
// diff-label, ag = max a over {diff-label, a < aHi}. fmax associative ->
// plain partial stores deterministic. 0-conflict swizzle staging.
// ---------------------------------------------------------------------------
__global__ __launch_bounds__(512) void k_main(const _Float16* __restrict__ hp,
                                              const int* __restrict__ labels,
                                              const float* __restrict__ dpos,
                                              float* __restrict__ pr_n,
                                              float* __restrict__ pr_s,
                                              float* __restrict__ pc_n,
                                              float* __restrict__ pc_s) {
    __shared__ char Abuf[2][BM * 128];   // 16 KB each
    __shared__ char Bbuf[2][BN * 128];
    __shared__ float rHi[BM], cHi[BN];
    __shared__ int rlab[BM], clab[BN];
    __shared__ float tmpn[4][BM], tmps[4][BM];

    const int t = threadIdx.x;
    int tb = blockIdx.x;
    // triangular decode: tb -> (by, bx), by <= bx
    int by = (int)((2 * NB + 1 - sqrtf((float)((2 * NB + 1) * (2 * NB + 1)) -
                                       8.0f * (float)tb)) * 0.5f);
    if (by < 0) by = 0;
    if (by > NB - 1) by = NB - 1;
    while (by > 0 && (by * NB - by * (by - 1) / 2) > tb) --by;
    while (((by + 1) * NB - (by + 1) * by / 2) <= tb) ++by;
    const int bx = by + (tb - (by * NB - by * (by - 1) / 2));
    const int r0 = by * BM, c0 = bx * BN;

    const int w = t >> 6, lane = t & 63;
    const int wr = w >> 2, wc = w & 3;   // 2x4 wave grid; 64x32 per wave

    if (t < BM) {
        rlab[t] = labels[r0 + t];
        float dp = dpos[r0 + t];
        rHi[t] = (2.0f - dp * dp) * 0.5f;   // a < aHi <=> dist > dp
    } else if (t < 256) {
        int u = t - BM;
        clab[u] = labels[c0 + u];
        float dp = dpos[c0 + u];
        cHi[u] = (2.0f - dp * dp) * 0.5f;
    }

    f32x4 acc[4][2] = {};    // [m][n]
    f32x4 accT[2][4] = {};   // [n][m]

    const int srow = lane >> 3;
    const int scol = ((lane & 7) ^ srow) << 3;   // fp16-elem offset
    const _Float16* gA0 = hp + (size_t)(r0 + srow) * D + scol + (size_t)w * 8 * D;
    const _Float16* gB0 = hp + (size_t)(c0 + srow) * D + scol + (size_t)w * 8 * D;
    const int ldso = w * 1024 + lane * 16;

#define STAGE(bufA, bufB, k0e)                                                  \
    {                                                                           \
        _Pragma("unroll")                                                       \
        for (int q = 0; q < 2; ++q) {                                           \
            const _Float16* gpa = gA0 + q * (8 * 8 * D) + (k0e);                \
            const _Float16* gpb = gB0 + q * (8 * 8 * D) + (k0e);                \
            char* lpa = (bufA) + q * 8192 + ldso;                               \
            char* lpb = (bufB) + q * 8192 + ldso;                               \
            __builtin_amdgcn_global_load_lds(                                   \
                (__attribute__((address_space(1))) void*)(void*)gpa,            \
                (__attribute__((address_space(3))) void*)lpa, 16, 0, 0);        \
            __builtin_amdgcn_global_load_lds(                                   \
                (__attribute__((address_space(1))) void*)(void*)gpb,            \
                (__attribute__((address_space(3))) void*)lpb, 16, 0, 0);        \
        }                                                                       \
    }

    STAGE(Abuf[0], Bbuf[0], 0);
    asm volatile("s_waitcnt vmcnt(0)" ::: "memory");
    __syncthreads();

    const int g2 = lane >> 4;
    const int lr = lane & 15;
    const int rsw = lr & 7;

#pragma unroll 1
    for (int s = 0; s < NCH; ++s) {
        const int cur = s & 1;
        if (s < NCH - 1) STAGE(Abuf[cur ^ 1], Bbuf[cur ^ 1], (s + 1) * 64);

#pragma unroll
        for (int kk = 0; kk < 2; ++kk) {
            const int cb = kk * 64 + (g2 << 4);
            half8 aF[4], bF[2];
#pragma unroll
            for (int m = 0; m < 4; ++m) {
                int ra = wr * 64 + m * 16 + lr;
                aF[m] = *reinterpret_cast<const half8*>(
                    Abuf[cur] + ra * 128 + (cb ^ (rsw << 4)));
            }
#pragma unroll
            for (int n = 0; n < 2; ++n) {
                int rb = wc * 32 + n * 16 + lr;
                bF[n] = *reinterpret_cast<const half8*>(
                    Bbuf[cur] + rb * 128 + (cb ^ (rsw << 4)));
            }
#pragma unroll
            for (int m = 0; m < 4; ++m)
#pragma unroll
                for (int n = 0; n < 2; ++n)
                    acc[m][n] = __builtin_amdgcn_mfma_f32_16x16x32_f16(
                        aF[m], bF[n], acc[m][n], 0, 0, 0);
#pragma unroll
            for (int n = 0; n < 2; ++n)
#pragma unroll
                for (int m = 0; m < 4; ++m)
                    accT[n][m] = __builtin_amdgcn_mfma_f32_16x16x32_f16(
                        bF[n], aF[m], accT[n][m], 0, 0, 0);
        }
        __syncthreads();
    }
#undef STAGE

    // ---- epilogue: key-free float maxima ----
    const float NINF = -__builtin_inff();

    int rowm[4]; int rlm[4]; float rHim[4];
#pragma unroll
    for (int m = 0; m < 4; ++m) {
        rowm[m] = wr * 64 + m * 16 + lr;
        rlm[m] = rlab[rowm[m]];
        rHim[m] = rHi[rowm[m]];
    }
    int4 clA = *reinterpret_cast<const int4*>(&clab[wc * 32 + g2 * 4]);
    int4 clB = *reinterpret_cast<const int4*>(&clab[wc * 32 + 16 + g2 * 4]);
    const int clv[8] = {clA.x, clA.y, clA.z, clA.w, clB.x, clB.y, clB.z, clB.w};
    int coln[2]; int cln[2]; float cHin[2];
#pragma unroll
    for (int n = 0; n < 2; ++n) {
        coln[n] = wc * 32 + n * 16 + lr;
        cln[n] = clab[coln[n]];
        cHin[n] = cHi[coln[n]];
    }
    int rlq[16];
#pragma unroll
    for (int m = 0; m < 4; ++m) {
        int4 rv = *reinterpret_cast<const int4*>(&rlab[wr * 64 + m * 16 + g2 * 4]);
        rlq[m * 4 + 0] = rv.x; rlq[m * 4 + 1] = rv.y;
        rlq[m * 4 + 2] = rv.z; rlq[m * 4 + 3] = rv.w;
    }

    // row pass via accT
#pragma unroll
    for (int m = 0; m < 4; ++m) {
        const int rl = rlm[m];
        const float aHi = rHim[m];
        float an = NINF, ag = NINF;
#pragma unroll
        for (int n = 0; n < 2; ++n)
#pragma unroll
            for (int reg = 0; reg < 4; ++reg) {
                float a = accT[n][m][reg];
                bool neq = (rl != clv[n * 4 + reg]);
                an = fmaxf(an, neq ? a : NINF);
                ag = fmaxf(ag, (neq && a < aHi) ? a : NINF);
            }
        an = fmaxf(an, __shfl_xor(an, 16, 64));
        an = fmaxf(an, __shfl_xor(an, 32, 64));
        ag = fmaxf(ag, __shfl_xor(ag, 16, 64));
        ag = fmaxf(ag, __shfl_xor(ag, 32, 64));
        if (g2 == 0) {
            tmpn[wc][rowm[m]] = an;
            tmps[wc][rowm[m]] = ag;
        }
    }
    __syncthreads();
    if (t < BM) {
        float a0 = fmaxf(tmpn[0][t], tmpn[1][t]);
        float a1 = fmaxf(tmpn[2][t], tmpn[3][t]);
        pr_n[(size_t)tb * BM + t] = fmaxf(a0, a1);
        float b0 = fmaxf(tmps[0][t], tmps[1][t]);
        float b1 = fmaxf(tmps[2][t], tmps[3][t]);
        pr_s[(size_t)tb * BM + t] = fmaxf(b0, b1);
    }
    __syncthreads();

    // col pass via acc
#pragma unroll
    for (int n = 0; n < 2; ++n) {
        const int cl = cln[n];
        const float aHi = cHin[n];
        float an = NINF, ag = NINF;
#pragma unroll
        for (int m = 0; m < 4; ++m)
#pragma unroll
            for (int reg = 0; reg < 4; ++reg) {
                float a = acc[m][n][reg];
                bool neq = (cl != rlq[m * 4 + reg]);
                an = fmaxf(an, neq ? a : NINF);
                ag = fmaxf(ag, (neq && a < aHi) ? a : NINF);
            }
        an = fmaxf(an, __shfl_xor(an, 16, 64));
        an = fmaxf(an, __shfl_xor(an, 32, 64));
        ag = fmaxf(ag, __shfl_xor(ag, 16, 64));
        ag = fmaxf(ag, __shfl_xor(ag, 32, 64));
        if (lane < 16) {
            tmpn[wr][coln[n]] = an;
            tmps[wr][coln[n]] = ag;
        }
    }
    __syncthreads();
    if (t < BN) {
        pc_n[(size_t)tb * BN + t] = fmaxf(tmpn[0][t], tmpn[1][t]);
        pc_s[(size_t)tb * BN + t] = fmaxf(tmps[0][t], tmps[1][t]);
    }
}

// ---------------------------------------------------------------------------
// k_finish: 64 blocks; coalesced fmax folds of the per-tile partials; loss
// from exact f32 maxima; deterministic packed-integer atomicAdd finish.
// ---------------------------------------------------------------------------
__global__ __launch_bounds__(256) void k_finish(const float* __restrict__ dpos,
                                                const float* __restrict__ pr_n,
                                                const float* __restrict__ pr_s,
                                                const float* __restrict__ pc_n,
                                                const float* __restrict__ pc_s,
                                                u64* __restrict__ acc_pack,
                                                unsigned* __restrict__ counter,
                                                float* __restrict__ out) {
    __shared__ float shn[2][128], shs[2][128];
    __shared__ u64 wpart[2];
    const int q = blockIdx.x;
    const int t = threadIdx.x;
    const int half = t >> 7, a = t & 127;
    const int Lr = NB - q;
    const int base = q * NB - q * (q - 1) / 2;
    const int ntiles = Lr + q + 1;
    const float NINF = -__builtin_inff();

    float an = NINF, ag = NINF;
    for (int u = half; u < ntiles; u += 2) {
        size_t off;
        const float *Pn, *Ps;
        if (u < Lr) {
            off = (size_t)(base + u) * BM + a;
            Pn = pr_n; Ps = pr_s;
        } else {
            int byy = u - Lr;
            int tb2 = byy * NB - byy * (byy - 1) / 2 + (q - byy);
            off = (size_t)tb2 * BN + a;
            Pn = pc_n; Ps = pc_s;
        }
        an = fmaxf(an, Pn[off]);
        ag = fmaxf(ag, Ps[off]);
    }
    shn[half][a] = an;
    shs[half][a] = ag;
    __syncthreads();

    u64 pack = 0;
    if (t < 128) {
        an = fmaxf(shn[0][t], shn[1][t]);
        ag = fmaxf(shs[0][t], shs[1][t]);
        float dp = dpos[q * 128 + t];
        if (dp >= 0.0f && an > -1e37f) {
            float dphi = dp + MARGIN;
            float aLo = (2.0f - dphi * dphi) * 0.5f;   // a > aLo <=> dist < dp+m
            float asel = (ag > aLo) ? ag : an;
            float fsq = fmaxf(fmaf(-2.0f, asel, 2.0f), 0.0f);
            float dn = sqrtf(fsq);
            float l = fmaxf(dp - dn + MARGIN, 0.0f);
            u64 lq = (u64)(l * 1073741824.0f + 0.5f);   // 2^30 fixed point
            pack = (lq << 16) | 1ull;
        }
    }
    for (int m = 1; m <= 32; m <<= 1) pack += __shfl_xor(pack, m, 64);
    if (t < 128 && (t & 63) == 0) wpart[t >> 6] = pack;
    __syncthreads();
    if (t == 0) {
        atomicAdd(acc_pack, wpart[0] + wpart[1]);
        __threadfence();
        unsigned old = atomicAdd(counter, 1u);
        if (old == gridDim.x - 1) {
            u64 val = atomicAdd(acc_pack, (u64)0);
            double s = (double)(val >> 16) * (1.0 / 1073741824.0);
            double c = (double)(val & 0xFFFFull);
            out[0] = (float)(s / c);
        }
    }
}

// ---------------------------------------------------------------------------
extern "C" void kernel_launch(void* const* d_in, const int* in_sizes, int n_in,
                              void* d_out, int out_size, void* d_ws, size_t ws_size,
                              hipStream_t stream) {
    const float* x = (const float*)d_in[0];
    const int* labels = (const int*)d_in[1];
    float* out = (float*)d_out;

    u64* acc_pack = (u64*)d_ws;
    unsigned* counter = (unsigned*)(acc_pack + 1);
    float* dpos = (float*)(counter + 2);
    _Float16* hp = (_Float16*)(dpos + N);
    float* pr_n = (float*)(hp + (size_t)N * D);
    float* pr_s = pr_n + (size_t)NTRI * BM;
    float* pc_n = pr_s + (size_t)NTRI * BM;
    float* pc_s = pc_n + (size_t)NTRI * BM;

    hipLaunchKernelGGL(k_prep, dim3(NCONV + NCLS), dim3(256), 0, stream,
                       x, labels, hp, dpos, acc_pack, counter);
    hipLaunchKernelGGL(k_main, dim3(NTRI), dim3(512), 0, stream,
                       hp, labels, dpos, pr_n, pr_s, pc_n, pc_s);
    hipLaunchKernelGGL(k_finish, dim3(NB), dim3(256), 0, stream,
                       dpos, pr_n, pr_s, pc_n, pc_s, acc_pack, counter, out);
}